// Round 3
// baseline (129.727 us; speedup 1.0000x reference)
//
#include <hip/hip_runtime.h>

// SConv2dAvg: out[b,o,y,x] = sum_{c,kh,kw} in[b,c,2y+selh+kh,2x+selw+kw] * W[o,c,kh,kw] + bias[o]
// B=16 Cin=64 H=W=128 Cout=64 oh=ow=63 stride=2, fp32 in/out.
// Round 6: occupancy-fixed stage 2 (M=32 tile).
//  - Wave wv owns Cout group 16*wv..+15 with 72 VGPRs of register-resident weights.
//  - A tile [u=cc*9+tap][32 m][32 ch] = 36.9 KB -> 4 blocks/CU; VGPR <= 128 via
//    __launch_bounds__(256,4) -> 16 waves/CU (was 8).
//  - One-shot async stage via global_load_lds width=16: wave (row-half, cc-half)
//    stages 9 slabs, 9 loads/lane, ONE vmcnt drain at the single pre-compute barrier.
//  - Compute: 18 K-steps x (2 ds_read_b128 + 2 MFMA)/wave, conflict-free.

#define B_    16
#define CIN   64
#define H_    128
#define W_    128
#define COUT  64
#define OH    63
#define OW    63
#define NPIX  (OH * OW)      // 3969
#define KTOT  (CIN * 9)      // 576

typedef short  short8  __attribute__((ext_vector_type(8)));
typedef float  float4v __attribute__((ext_vector_type(4)));

__device__ inline short f2bf(float f) {     // RN-to-even fp32 -> bf16 bits
    union { float f; unsigned u; } x; x.f = f;
    unsigned r = x.u + 0x7fffu + ((x.u >> 16) & 1u);
    return (short)(r >> 16);
}

// ---------------- stage 1: input NCHW fp32 -> NHWC bf16  (+ fused weight repack) ----------------
__global__ __launch_bounds__(256)
void repack_bf16(const float* __restrict__ in, const float* __restrict__ wgt,
                 short* __restrict__ nhwc, short* __restrict__ wgt_t) {
    if (blockIdx.y == H_) {                 // weight duty: (o,c,tap) fp32 -> (o,tap,c) bf16
        const int bid = blockIdx.z * 2 + blockIdx.x;           // 0..31
        for (int e = bid * 256 + (int)threadIdx.x; e < COUT * KTOT; e += 32 * 256) {
            const int o   = e / KTOT;
            const int rem = e - o * KTOT;
            const int c   = rem / 9;
            const int tap = rem - c * 9;
            wgt_t[o * KTOT + tap * CIN + c] = f2bf(wgt[e]);
        }
        return;
    }

    __shared__ float T[64 * 65];            // T[c][w], pad 65
    const int tid = threadIdx.x;
    const int w0  = blockIdx.x * 64;
    const int h   = blockIdx.y;
    const int b   = blockIdx.z;

    {   // load 64c x 64w, coalesced along w
        const int w4 = tid & 15;
        const int cl = tid >> 4;
#pragma unroll
        for (int i = 0; i < 4; ++i) {
            const int c = cl + 16 * i;
            const float4 v = *(const float4*)&in[((b * CIN + c) * H_ + h) * W_ + w0 + 4 * w4];
            T[c * 65 + 4 * w4 + 0] = v.x;
            T[c * 65 + 4 * w4 + 1] = v.y;
            T[c * 65 + 4 * w4 + 2] = v.z;
            T[c * 65 + 4 * w4 + 3] = v.w;
        }
    }
    __syncthreads();
    {   // store: 8 channels/thread as one 16B bf16 vector, coalesced along c
        const int cg = tid & 7;             // channel group (8 ch)
        const int wl = tid >> 3;            // 0..31
#pragma unroll
        for (int i = 0; i < 2; ++i) {
            const int w = wl + 32 * i;
            short8 v;
#pragma unroll
            for (int t = 0; t < 8; ++t)
                v[t] = f2bf(T[(8 * cg + t) * 65 + w]);
            *(short8*)&nhwc[((b * H_ + h) * W_ + w0 + w) * CIN + 8 * cg] = v;
        }
    }
}

// ---------------- stage 2: B-in-registers, A-async-LDS MFMA implicit GEMM ----------------
// block: 16 pixels x 2 batches (M=32) x 64 Cout, 256 threads = 4 waves.
#define PIXT  16
#define BT    2
#define LDO   65    // epilogue staging stride (floats)

__global__ __launch_bounds__(256, 4)
void sconv2davg_mfma(const short* __restrict__ nhwc,
                     const short* __restrict__ wgt_t,
                     const float* __restrict__ bias,
                     const int* __restrict__ selh,
                     const int* __restrict__ selw,
                     float* __restrict__ out) {
    __shared__ __align__(16) short As[18 * 1024];   // [u][m=32][32ch]  36.9 KB

    const int tid = threadIdx.x;
    const int p0  = blockIdx.x * PIXT;
    const int b0  = blockIdx.y * BT;

    const int ln = tid & 15;                // MFMA col within 16
    const int hl = (tid >> 4) & 3;          // k-quad: channels hl*8..hl*8+7
    const int wv = tid >> 6;                // wave id = Cout group
    const int l  = tid & 63;                // lane

    // ---- B: this wave's full-K weight panel -> 18 x short8 = 72 VGPRs ----
    const short* Bp = &wgt_t[(16 * wv + ln) * KTOT + hl * 8];
    short8 Bv[18];
#pragma unroll
    for (int u = 0; u < 18; ++u) {
        const int cc = u / 9, tap = u - 9 * (u / 9);
        Bv[u] = *(const short8*)&Bp[tap * CIN + cc * 32];
    }

    // ---- A: async stage; wave (w01 = row-half, wcc = cc-half) stages 9 slabs ----
    {
        const int w01 = wv & 1;                 // rows 16*w01 .. +15
        const int wcc = wv >> 1;                // channel chunk 0/1
        const int mst = 16 * w01 + (l >> 2);    // staged M row 0..31
        const int pl  = mst >> 1;               // BT=2
        const int bl  = mst & 1;
        int p = p0 + pl;
        if (p > NPIX - 1) p = NPIX - 1;         // tail clamp; stores guarded
        const int y   = p / OW;
        const int x   = p - y * OW;
        const int ih0 = 2 * y + selh[p];
        const int iw0 = 2 * x + selw[p];
        const short* src0 =
            &nhwc[(((b0 + bl) * H_ + ih0) * W_ + iw0) * CIN + wcc * 32 + (l & 3) * 8];
        short* dst0 = &As[wcc * 9 * 1024 + w01 * 512] + l * 8;  // linear-in-lane dest
#pragma unroll
        for (int tap = 0; tap < 9; ++tap) {
            const int kh = tap / 3, kw = tap - 3 * (tap / 3);
            __builtin_amdgcn_global_load_lds(
                (const __attribute__((address_space(1))) void*)
                    (src0 + kh * (W_ * CIN) + kw * CIN),
                (__attribute__((address_space(3))) void*)(dst0 + tap * 1024),
                16, 0, 0);
        }
    }
    __syncthreads();                            // single vmcnt drain (B regs + A LDS)

    // ---- compute: 18 K-steps x (2 ds_read_b128 + 2 MFMA), B from regs ----
    float4v acc[2];
#pragma unroll
    for (int i = 0; i < 2; ++i) acc[i] = (float4v){0.f, 0.f, 0.f, 0.f};
#pragma unroll
    for (int u = 0; u < 18; ++u) {
#pragma unroll
        for (int i = 0; i < 2; ++i) {
            const short8 a = *(const short8*)
                &As[u * 1024 + (16 * i + ln) * 32 + hl * 8];
            acc[i] = __builtin_amdgcn_mfma_f32_16x16x32_bf16(a, Bv[u], acc[i], 0, 0, 0);
        }
    }
    __syncthreads();                            // all A reads done; reuse As as Ot

    // ---- epilogue: C/D col=ln, row=4*hl+r; m = 16*i + 4*hl + r; o = 16*wv + ln ----
    float* Ot = (float*)As;                     // 32 x 65 floats = 8.3 KB
    const float bv = bias[16 * wv + ln];
#pragma unroll
    for (int i = 0; i < 2; ++i)
#pragma unroll
        for (int r = 0; r < 4; ++r)
            Ot[(16 * i + 4 * hl + r) * LDO + 16 * wv + ln] = acc[i][r] + bv;
    __syncthreads();
    {
        const int pp = tid & 15;                // pixel within tile
        const int rr = tid >> 4;                // 0..15
        const int p2 = p0 + pp;
        if (p2 < NPIX) {
#pragma unroll
            for (int k = 0; k < 8; ++k) {
                const int rid = k * 16 + rr;    // 0..127 = b2*64 + o
                const int b2  = rid >> 6;
                const int o   = rid & 63;
                out[((b0 + b2) * COUT + o) * NPIX + p2] = Ot[(pp * 2 + b2) * LDO + o];
            }
        }
    }
}

// ---------------- fallback (round-1 kernel) if ws too small ----------------
#define FKC   72
#define FLDA  76
__global__ __launch_bounds__(256, 4)
void sconv2davg_fallback(const float* __restrict__ in,
                         const float* __restrict__ wgt,
                         const float* __restrict__ bias,
                         const int* __restrict__ selh,
                         const int* __restrict__ selw,
                         float* __restrict__ out) {
    __shared__ float As[64 * FLDA];
    __shared__ float Ws[64 * FLDA];
    __shared__ int hb_s[4], wb_s[4];
    const int tid = threadIdx.x;
    const int p0  = blockIdx.x * 4;
    if (tid < 4) {
        int p = p0 + tid;
        if (p > NPIX - 1) p = NPIX - 1;
        int y = p / OW;
        int x = p - y * OW;
        hb_s[tid] = 2 * y + selh[p];
        wb_s[tid] = 2 * x + selw[p];
    }
    __syncthreads();
    const int tn = tid & 15, tm = tid >> 4;
    float acc[4][4];
#pragma unroll
    for (int i = 0; i < 4; ++i)
#pragma unroll
        for (int j = 0; j < 4; ++j) acc[i][j] = 0.0f;
    for (int cc = 0; cc < 8; ++cc) {
        const int c0 = cc * 8;
#pragma unroll
        for (int it = 0; it < 18; ++it) {
            int idx = tid + it * 256;
            int m = idx / FKC, rem = idx - m * FKC;
            int cl = rem / 9, r = rem - cl * 9;
            int kh = r / 3, kw = r - kh * 3;
            As[m * FLDA + rem] =
                in[((((m & 15) * CIN) + (c0 + cl)) * H_ + hb_s[m >> 4] + kh) * W_ + wb_s[m >> 4] + kw];
        }
#pragma unroll
        for (int it = 0; it < 18; ++it) {
            int idx = tid + it * 256;
            int o = idx / FKC, kk = idx - o * FKC;
            Ws[o * FLDA + kk] = wgt[o * KTOT + cc * FKC + kk];
        }
        __syncthreads();
#pragma unroll 2
        for (int k0 = 0; k0 < FKC; k0 += 4) {
            float4 a[4], w[4];
#pragma unroll
            for (int i = 0; i < 4; ++i) a[i] = *(const float4*)&As[(4 * tm + i) * FLDA + k0];
#pragma unroll
            for (int j = 0; j < 4; ++j) w[j] = *(const float4*)&Ws[(tn + 16 * j) * FLDA + k0];
#pragma unroll
            for (int i = 0; i < 4; ++i)
#pragma unroll
                for (int j = 0; j < 4; ++j) {
                    acc[i][j] += a[i].x * w[j].x; acc[i][j] += a[i].y * w[j].y;
                    acc[i][j] += a[i].z * w[j].z; acc[i][j] += a[i].w * w[j].w;
                }
        }
        __syncthreads();
    }
    const int p = p0 + (tm >> 2);
    if (p < NPIX) {
#pragma unroll
        for (int i = 0; i < 4; ++i) {
            int b = (tm & 3) * 4 + i;
#pragma unroll
            for (int j = 0; j < 4; ++j)
                out[((b * COUT) + tn + 16 * j) * NPIX + p] = acc[i][j] + bias[tn + 16 * j];
        }
    }
}

extern "C" void kernel_launch(void* const* d_in, const int* in_sizes, int n_in,
                              void* d_out, int out_size, void* d_ws, size_t ws_size,
                              hipStream_t stream) {
    const float* in   = (const float*)d_in[0];
    const float* wgt  = (const float*)d_in[1];
    const float* bias = (const float*)d_in[2];
    const int*   selh = (const int*)d_in[3];
    const int*   selw = (const int*)d_in[4];
    float* out = (float*)d_out;

    const size_t nhwc_elems = (size_t)B_ * H_ * W_ * CIN;            // 16.7M bf16
    const size_t need = (nhwc_elems + (size_t)COUT * KTOT) * 2;      // ~33.6 MB

    if (ws_size >= need) {
        short* nhwc  = (short*)d_ws;
        short* wgt_t = nhwc + nhwc_elems;
        // y==H_ slice of the grid does the weight repack (32 blocks)
        repack_bf16<<<dim3(W_ / 64, H_ + 1, B_), 256, 0, stream>>>(in, wgt, nhwc, wgt_t);
        const int ptiles = (NPIX + PIXT - 1) / PIXT;                 // 249
        sconv2davg_mfma<<<dim3(ptiles, B_ / BT), 256, 0, stream>>>(
            nhwc, wgt_t, bias, selh, selw, out);
    } else {
        sconv2davg_fallback<<<(NPIX + 3) / 4, 256, 0, stream>>>(
            in, wgt, bias, selh, selw, out);
    }
}

// Round 5
// 120.812 us; speedup vs baseline: 1.0738x; 1.0738x over previous
//
#include <hip/hip_runtime.h>

// SConv2dAvg: out[b,o,y,x] = sum_{c,kh,kw} in[b,c,2y+selh+kh,2x+selw+kw] * W[o,c,kh,kw] + bias[o]
// B=16 Cin=64 H=W=128 Cout=64 oh=ow=63 stride=2, fp32 in/out.
// Round 8: R7 pipeline + the missing compute->epilogue barrier (R7 raced: Ot
// fp32 writes overlaid As[cur] while other waves still ds_read it as bf16).
//  - Each block: 64 consecutive pixels (4 tiles of 16) x 2 batches x 64 Cout.
//  - B panel register-resident (72 VGPR), loaded ONCE per block (amortized 4x).
//  - A: [buf][u=cc*9+tap][32 m][32 ch], 2 x 36.9 KB; stage(t+1) issued before
//    compute(t); compute (~1700cy) covers HBM latency; barrier drain cheap.
//  - 3 barriers/tile: post-compute (protects Ot overlay), post-Ot-write,
//    post-store (protects Ot region from reuse next tile).

#define B_    16
#define CIN   64
#define H_    128
#define W_    128
#define COUT  64
#define OH    63
#define OW    63
#define NPIX  (OH * OW)      // 3969
#define KTOT  (CIN * 9)      // 576

typedef short  short8  __attribute__((ext_vector_type(8)));
typedef float  float4v __attribute__((ext_vector_type(4)));

__device__ inline short f2bf(float f) {     // RN-to-even fp32 -> bf16 bits
    union { float f; unsigned u; } x; x.f = f;
    unsigned r = x.u + 0x7fffu + ((x.u >> 16) & 1u);
    return (short)(r >> 16);
}

// ---------------- stage 1: input NCHW fp32 -> NHWC bf16  (+ fused weight repack) ----------------
__global__ __launch_bounds__(256)
void repack_bf16(const float* __restrict__ in, const float* __restrict__ wgt,
                 short* __restrict__ nhwc, short* __restrict__ wgt_t) {
    if (blockIdx.y == H_) {                 // weight duty: (o,c,tap) fp32 -> (o,tap,c) bf16
        const int bid = blockIdx.z * 2 + blockIdx.x;           // 0..31
        for (int e = bid * 256 + (int)threadIdx.x; e < COUT * KTOT; e += 32 * 256) {
            const int o   = e / KTOT;
            const int rem = e - o * KTOT;
            const int c   = rem / 9;
            const int tap = rem - c * 9;
            wgt_t[o * KTOT + tap * CIN + c] = f2bf(wgt[e]);
        }
        return;
    }

    __shared__ float T[64 * 65];            // T[c][w], pad 65
    const int tid = threadIdx.x;
    const int w0  = blockIdx.x * 64;
    const int h   = blockIdx.y;
    const int b   = blockIdx.z;

    {   // load 64c x 64w, coalesced along w
        const int w4 = tid & 15;
        const int cl = tid >> 4;
#pragma unroll
        for (int i = 0; i < 4; ++i) {
            const int c = cl + 16 * i;
            const float4 v = *(const float4*)&in[((b * CIN + c) * H_ + h) * W_ + w0 + 4 * w4];
            T[c * 65 + 4 * w4 + 0] = v.x;
            T[c * 65 + 4 * w4 + 1] = v.y;
            T[c * 65 + 4 * w4 + 2] = v.z;
            T[c * 65 + 4 * w4 + 3] = v.w;
        }
    }
    __syncthreads();
    {   // store: 8 channels/thread as one 16B bf16 vector, coalesced along c
        const int cg = tid & 7;             // channel group (8 ch)
        const int wl = tid >> 3;            // 0..31
#pragma unroll
        for (int i = 0; i < 2; ++i) {
            const int w = wl + 32 * i;
            short8 v;
#pragma unroll
            for (int t = 0; t < 8; ++t)
                v[t] = f2bf(T[(8 * cg + t) * 65 + w]);
            *(short8*)&nhwc[((b * H_ + h) * W_ + w0 + w) * CIN + 8 * cg] = v;
        }
    }
}

// ---------------- stage 2: pipelined B-in-registers, A-async-LDS MFMA ----------------
#define PIXT  16
#define BT    2
#define NT    4
#define TILE_SH (18 * 1024)  // shorts per A buffer
#define LDO   65             // epilogue staging stride (floats)

__global__ __launch_bounds__(256, 2)
void sconv2davg_mfma(const short* __restrict__ nhwc,
                     const short* __restrict__ wgt_t,
                     const float* __restrict__ bias,
                     const int* __restrict__ selh,
                     const int* __restrict__ selw,
                     float* __restrict__ out) {
    __shared__ __align__(16) short As[2 * TILE_SH];   // 73.7 KB (2 x [u][32m][32ch])

    const int tid = threadIdx.x;
    const int p00 = blockIdx.x * (PIXT * NT);         // 64 pixels per block
    const int b0  = blockIdx.y * BT;

    const int ln = tid & 15;                // MFMA col within 16
    const int hl = (tid >> 4) & 3;          // k-quad: channels hl*8..hl*8+7
    const int wv = tid >> 6;                // wave id = Cout group
    const int l  = tid & 63;                // lane

    // ---- B: this wave's full-K weight panel -> 18 x short8 = 72 VGPRs ----
    const short* Bp = &wgt_t[(16 * wv + ln) * KTOT + hl * 8];
    short8 Bv[18];
#pragma unroll
    for (int u = 0; u < 18; ++u) {
        const int cc = u / 9, tap = u - 9 * (u / 9);
        Bv[u] = *(const short8*)&Bp[tap * CIN + cc * 32];
    }

    // ---- staging lane geometry (fixed across tiles) ----
    const int w01 = wv & 1;                 // row-half: rows 16*w01 .. +15
    const int wcc = wv >> 1;                // channel chunk 0/1
    const int mst = 16 * w01 + (l >> 2);    // staged M row 0..31
    const int pl  = mst >> 1;               // BT=2
    const int bl  = mst & 1;

    // preload sel/base coords for my NT tiles into registers
    int ih0v[NT], iw0v[NT];
#pragma unroll
    for (int t = 0; t < NT; ++t) {
        int p = p00 + t * PIXT + pl;
        if (p > NPIX - 1) p = NPIX - 1;     // tail clamp; stores guarded
        const int y = p / OW;
        const int x = p - y * OW;
        ih0v[t] = 2 * y + selh[p];
        iw0v[t] = 2 * x + selw[p];
    }

    const short* abase = &nhwc[((size_t)(b0 + bl) * H_) * W_ * CIN + wcc * 32 + (l & 3) * 8];
    short* dstw = &As[wcc * (9 * 1024) + w01 * 512] + l * 8;   // linear-in-lane dest

#define STAGE(t, bsel)                                                          \
    {                                                                           \
        const short* src0 = abase + (ih0v[t] * W_ + iw0v[t]) * CIN;             \
        short* dst0 = dstw + (bsel) * TILE_SH;                                  \
        _Pragma("unroll")                                                       \
        for (int tap = 0; tap < 9; ++tap) {                                     \
            const int kh = tap / 3, kw = tap - 3 * (tap / 3);                   \
            __builtin_amdgcn_global_load_lds(                                   \
                (const __attribute__((address_space(1))) void*)                 \
                    (src0 + kh * (W_ * CIN) + kw * CIN),                        \
                (__attribute__((address_space(3))) void*)(dst0 + tap * 1024),   \
                16, 0, 0);                                                      \
        }                                                                       \
    }

    STAGE(0, 0);
    __syncthreads();                        // drain tile-0 stage

    const float bv = bias[16 * wv + ln];
    const int pp = tid & 15;                // epilogue: pixel within tile
    const int rr = tid >> 4;                // 0..15

#pragma unroll
    for (int t = 0; t < NT; ++t) {
        const int cur = t & 1;
        if (t + 1 < NT) STAGE(t + 1, (t + 1) & 1);   // async into other buffer

        // ---- compute: 18 K-steps x (2 ds_read_b128 + 2 MFMA), B from regs ----
        float4v acc[2];
#pragma unroll
        for (int i = 0; i < 2; ++i) acc[i] = (float4v){0.f, 0.f, 0.f, 0.f};
#pragma unroll
        for (int u = 0; u < 18; ++u) {
#pragma unroll
            for (int i = 0; i < 2; ++i) {
                const short8 a = *(const short8*)
                    &As[cur * TILE_SH + u * 1024 + (16 * i + ln) * 32 + hl * 8];
                acc[i] = __builtin_amdgcn_mfma_f32_16x16x32_bf16(a, Bv[u], acc[i], 0, 0, 0);
            }
        }
        __syncthreads();                    // ALL waves' A reads done before Ot overlay
                                            // (also drains stage(t+1) -- already covered
                                            //  by the ~1700cy compute above)

        // ---- epilogue into the just-freed buffer (cur) ----
        float* Ot = (float*)&As[cur * TILE_SH];       // 32 x 65 floats = 8.3 KB
#pragma unroll
        for (int i = 0; i < 2; ++i)
#pragma unroll
            for (int r = 0; r < 4; ++r)
                Ot[(16 * i + 4 * hl + r) * LDO + 16 * wv + ln] = acc[i][r] + bv;
        __syncthreads();                    // Ot visible to all waves
        {
            const int p2 = p00 + t * PIXT + pp;
            if (p2 < NPIX) {
#pragma unroll
                for (int k = 0; k < 8; ++k) {
                    const int rid = k * 16 + rr;      // 0..127 = b2*64 + o
                    const int b2  = rid >> 6;
                    const int o   = rid & 63;
                    out[((b0 + b2) * COUT + o) * NPIX + p2] = Ot[(pp * 2 + b2) * LDO + o];
                }
            }
        }
        __syncthreads();                    // Ot fully read before t+2 stages over it
    }
#undef STAGE
}

// ---------------- fallback (round-1 kernel) if ws too small ----------------
#define FKC   72
#define FLDA  76
__global__ __launch_bounds__(256, 4)
void sconv2davg_fallback(const float* __restrict__ in,
                         const float* __restrict__ wgt,
                         const float* __restrict__ bias,
                         const int* __restrict__ selh,
                         const int* __restrict__ selw,
                         float* __restrict__ out) {
    __shared__ float As[64 * FLDA];
    __shared__ float Ws[64 * FLDA];
    __shared__ int hb_s[4], wb_s[4];
    const int tid = threadIdx.x;
    const int p0  = blockIdx.x * 4;
    if (tid < 4) {
        int p = p0 + tid;
        if (p > NPIX - 1) p = NPIX - 1;
        int y = p / OW;
        int x = p - y * OW;
        hb_s[tid] = 2 * y + selh[p];
        wb_s[tid] = 2 * x + selw[p];
    }
    __syncthreads();
    const int tn = tid & 15, tm = tid >> 4;
    float acc[4][4];
#pragma unroll
    for (int i = 0; i < 4; ++i)
#pragma unroll
        for (int j = 0; j < 4; ++j) acc[i][j] = 0.0f;
    for (int cc = 0; cc < 8; ++cc) {
        const int c0 = cc * 8;
#pragma unroll
        for (int it = 0; it < 18; ++it) {
            int idx = tid + it * 256;
            int m = idx / FKC, rem = idx - m * FKC;
            int cl = rem / 9, r = rem - cl * 9;
            int kh = r / 3, kw = r - kh * 3;
            As[m * FLDA + rem] =
                in[((((m & 15) * CIN) + (c0 + cl)) * H_ + hb_s[m >> 4] + kh) * W_ + wb_s[m >> 4] + kw];
        }
#pragma unroll
        for (int it = 0; it < 18; ++it) {
            int idx = tid + it * 256;
            int o = idx / FKC, kk = idx - o * FKC;
            Ws[o * FLDA + kk] = wgt[o * KTOT + cc * FKC + kk];
        }
        __syncthreads();
#pragma unroll 2
        for (int k0 = 0; k0 < FKC; k0 += 4) {
            float4 a[4], w[4];
#pragma unroll
            for (int i = 0; i < 4; ++i) a[i] = *(const float4*)&As[(4 * tm + i) * FLDA + k0];
#pragma unroll
            for (int j = 0; j < 4; ++j) w[j] = *(const float4*)&Ws[(tn + 16 * j) * FLDA + k0];
#pragma unroll
            for (int i = 0; i < 4; ++i)
#pragma unroll
                for (int j = 0; j < 4; ++j) {
                    acc[i][j] += a[i].x * w[j].x; acc[i][j] += a[i].y * w[j].y;
                    acc[i][j] += a[i].z * w[j].z; acc[i][j] += a[i].w * w[j].w;
                }
        }
        __syncthreads();
    }
    const int p = p0 + (tm >> 2);
    if (p < NPIX) {
#pragma unroll
        for (int i = 0; i < 4; ++i) {
            int b = (tm & 3) * 4 + i;
#pragma unroll
            for (int j = 0; j < 4; ++j)
                out[((b * COUT) + tn + 16 * j) * NPIX + p] = acc[i][j] + bias[tn + 16 * j];
        }
    }
}

extern "C" void kernel_launch(void* const* d_in, const int* in_sizes, int n_in,
                              void* d_out, int out_size, void* d_ws, size_t ws_size,
                              hipStream_t stream) {
    const float* in   = (const float*)d_in[0];
    const float* wgt  = (const float*)d_in[1];
    const float* bias = (const float*)d_in[2];
    const int*   selh = (const int*)d_in[3];
    const int*   selw = (const int*)d_in[4];
    float* out = (float*)d_out;

    const size_t nhwc_elems = (size_t)B_ * H_ * W_ * CIN;            // 16.7M bf16
    const size_t need = (nhwc_elems + (size_t)COUT * KTOT) * 2;      // ~33.6 MB

    if (ws_size >= need) {
        short* nhwc  = (short*)d_ws;
        short* wgt_t = nhwc + nhwc_elems;
        // y==H_ slice of the grid does the weight repack (32 blocks)
        repack_bf16<<<dim3(W_ / 64, H_ + 1, B_), 256, 0, stream>>>(in, wgt, nhwc, wgt_t);
        const int pblocks = (NPIX + PIXT * NT - 1) / (PIXT * NT);    // 63
        sconv2davg_mfma<<<dim3(pblocks, B_ / BT), 256, 0, stream>>>(
            nhwc, wgt_t, bias, selh, selw, out);
    } else {
        sconv2davg_fallback<<<(NPIX + 3) / 4, 256, 0, stream>>>(
            in, wgt, bias, selh, selw, out);
    }
}

// Round 6
// 120.254 us; speedup vs baseline: 1.0788x; 1.0046x over previous
//
#include <hip/hip_runtime.h>

// SConv2dAvg: out[b,o,y,x] = sum_{c,kh,kw} in[b,c,2y+selh+kh,2x+selw+kw] * W[o,c,kh,kw] + bias[o]
// B=16 Cin=64 H=W=128 Cout=64 oh=ow=63 stride=2, fp32 in/out.
// Round 9: R8 pipeline + (a) minimal-waitcnt barriers (defer the vmcnt drain of
// stage(t+1) from post-compute to post-store: ~2x more latency cover), and
// (b) XCD-chunked work remap (by = bid&7: one batch-pair per XCD, y-rows in
// order -> adjacent blocks on an XCD share 2 of 4 gathered input rows in L2).
// Barrier hazard ledger (sync-structure edit -- treated as new template):
//   sync1 (As[cur] reads -> Ot overlay): s_barrier only. A wave's ds_reads are
//         consumed by its MFMAs (program order) before arrival; sched_barrier
//         fences compiler motion; stage DMAs target As[nxt] (disjoint).
//   sync2 (Ot ds_writes -> Ot ds_reads): lgkmcnt(0) + s_barrier.
//   sync3 (stage(t+1) DMA + stores -> next compute / Ot reuse): vmcnt(0) +
//         lgkmcnt(0) + s_barrier. Ot reads completed before their dependent
//         global_stores issued, so arrival implies reads done.

#define B_    16
#define CIN   64
#define H_    128
#define W_    128
#define COUT  64
#define OH    63
#define OW    63
#define NPIX  (OH * OW)      // 3969
#define KTOT  (CIN * 9)      // 576

typedef short  short8  __attribute__((ext_vector_type(8)));
typedef float  float4v __attribute__((ext_vector_type(4)));

__device__ inline short f2bf(float f) {     // RN-to-even fp32 -> bf16 bits
    union { float f; unsigned u; } x; x.f = f;
    unsigned r = x.u + 0x7fffu + ((x.u >> 16) & 1u);
    return (short)(r >> 16);
}

// minimal-waitcnt workgroup barriers (see hazard ledger above)
__device__ inline void bar_plain() {
    __builtin_amdgcn_sched_barrier(0);
    __builtin_amdgcn_s_barrier();
    __builtin_amdgcn_sched_barrier(0);
}
__device__ inline void bar_lgkm() {
    asm volatile("s_waitcnt lgkmcnt(0)" ::: "memory");
    __builtin_amdgcn_sched_barrier(0);
    __builtin_amdgcn_s_barrier();
    __builtin_amdgcn_sched_barrier(0);
}
__device__ inline void bar_full() {
    asm volatile("s_waitcnt vmcnt(0) lgkmcnt(0)" ::: "memory");
    __builtin_amdgcn_sched_barrier(0);
    __builtin_amdgcn_s_barrier();
    __builtin_amdgcn_sched_barrier(0);
}

// ---------------- stage 1: input NCHW fp32 -> NHWC bf16  (+ fused weight repack) ----------------
__global__ __launch_bounds__(256)
void repack_bf16(const float* __restrict__ in, const float* __restrict__ wgt,
                 short* __restrict__ nhwc, short* __restrict__ wgt_t) {
    if (blockIdx.y == H_) {                 // weight duty: (o,c,tap) fp32 -> (o,tap,c) bf16
        const int bid = blockIdx.z * 2 + blockIdx.x;           // 0..31
        for (int e = bid * 256 + (int)threadIdx.x; e < COUT * KTOT; e += 32 * 256) {
            const int o   = e / KTOT;
            const int rem = e - o * KTOT;
            const int c   = rem / 9;
            const int tap = rem - c * 9;
            wgt_t[o * KTOT + tap * CIN + c] = f2bf(wgt[e]);
        }
        return;
    }

    __shared__ float T[64 * 65];            // T[c][w], pad 65
    const int tid = threadIdx.x;
    const int w0  = blockIdx.x * 64;
    const int h   = blockIdx.y;
    const int b   = blockIdx.z;

    {   // load 64c x 64w, coalesced along w
        const int w4 = tid & 15;
        const int cl = tid >> 4;
#pragma unroll
        for (int i = 0; i < 4; ++i) {
            const int c = cl + 16 * i;
            const float4 v = *(const float4*)&in[((b * CIN + c) * H_ + h) * W_ + w0 + 4 * w4];
            T[c * 65 + 4 * w4 + 0] = v.x;
            T[c * 65 + 4 * w4 + 1] = v.y;
            T[c * 65 + 4 * w4 + 2] = v.z;
            T[c * 65 + 4 * w4 + 3] = v.w;
        }
    }
    __syncthreads();
    {   // store: 8 channels/thread as one 16B bf16 vector, coalesced along c
        const int cg = tid & 7;             // channel group (8 ch)
        const int wl = tid >> 3;            // 0..31
#pragma unroll
        for (int i = 0; i < 2; ++i) {
            const int w = wl + 32 * i;
            short8 v;
#pragma unroll
            for (int t = 0; t < 8; ++t)
                v[t] = f2bf(T[(8 * cg + t) * 65 + w]);
            *(short8*)&nhwc[((b * H_ + h) * W_ + w0 + w) * CIN + 8 * cg] = v;
        }
    }
}

// ---------------- stage 2: pipelined B-in-registers, A-async-LDS MFMA ----------------
#define PIXT  16
#define BT    2
#define NT    4
#define TILE_SH (18 * 1024)  // shorts per A buffer
#define LDO   65             // epilogue staging stride (floats)

__global__ __launch_bounds__(256, 2)
void sconv2davg_mfma(const short* __restrict__ nhwc,
                     const short* __restrict__ wgt_t,
                     const float* __restrict__ bias,
                     const int* __restrict__ selh,
                     const int* __restrict__ selw,
                     float* __restrict__ out) {
    __shared__ __align__(16) short As[2 * TILE_SH];   // 73.7 KB (2 x [u][32m][32ch])

    const int tid = threadIdx.x;
    // XCD-chunked remap: grid is flat 504 = 63 x 8; HW round-robins bid across
    // 8 XCDs, so bid&7 = XCD -> one batch-pair per XCD, y-rows visited in order.
    const int bid = blockIdx.x;
    const int bx  = bid >> 3;               // pixel-block 0..62 (row group)
    const int by  = bid & 7;                // batch-pair 0..7
    const int p00 = bx * (PIXT * NT);       // 64 pixels per block
    const int b0  = by * BT;

    const int ln = tid & 15;                // MFMA col within 16
    const int hl = (tid >> 4) & 3;          // k-quad: channels hl*8..hl*8+7
    const int wv = tid >> 6;                // wave id = Cout group
    const int l  = tid & 63;                // lane

    // ---- B: this wave's full-K weight panel -> 18 x short8 = 72 VGPRs ----
    const short* Bp = &wgt_t[(16 * wv + ln) * KTOT + hl * 8];
    short8 Bv[18];
#pragma unroll
    for (int u = 0; u < 18; ++u) {
        const int cc = u / 9, tap = u - 9 * (u / 9);
        Bv[u] = *(const short8*)&Bp[tap * CIN + cc * 32];
    }

    // ---- staging lane geometry (fixed across tiles) ----
    const int w01 = wv & 1;                 // row-half: rows 16*w01 .. +15
    const int wcc = wv >> 1;                // channel chunk 0/1
    const int mst = 16 * w01 + (l >> 2);    // staged M row 0..31
    const int pl  = mst >> 1;               // BT=2
    const int bl  = mst & 1;

    // preload sel/base coords for my NT tiles into registers
    int ih0v[NT], iw0v[NT];
#pragma unroll
    for (int t = 0; t < NT; ++t) {
        int p = p00 + t * PIXT + pl;
        if (p > NPIX - 1) p = NPIX - 1;     // tail clamp; stores guarded
        const int y = p / OW;
        const int x = p - y * OW;
        ih0v[t] = 2 * y + selh[p];
        iw0v[t] = 2 * x + selw[p];
    }

    const short* abase = &nhwc[((size_t)(b0 + bl) * H_) * W_ * CIN + wcc * 32 + (l & 3) * 8];
    short* dstw = &As[wcc * (9 * 1024) + w01 * 512] + l * 8;   // linear-in-lane dest

#define STAGE(t, bsel)                                                          \
    {                                                                           \
        const short* src0 = abase + (ih0v[t] * W_ + iw0v[t]) * CIN;             \
        short* dst0 = dstw + (bsel) * TILE_SH;                                  \
        _Pragma("unroll")                                                       \
        for (int tap = 0; tap < 9; ++tap) {                                     \
            const int kh = tap / 3, kw = tap - 3 * (tap / 3);                   \
            __builtin_amdgcn_global_load_lds(                                   \
                (const __attribute__((address_space(1))) void*)                 \
                    (src0 + kh * (W_ * CIN) + kw * CIN),                        \
                (__attribute__((address_space(3))) void*)(dst0 + tap * 1024),   \
                16, 0, 0);                                                      \
        }                                                                       \
    }

    STAGE(0, 0);
    __syncthreads();                        // prologue: full drain (tile-0 staged)

    const float bv = bias[16 * wv + ln];
    const int pp = tid & 15;                // epilogue: pixel within tile
    const int rr = tid >> 4;                // 0..15

#pragma unroll
    for (int t = 0; t < NT; ++t) {
        const int cur = t & 1;
        if (t + 1 < NT) STAGE(t + 1, (t + 1) & 1);   // async into other buffer

        // ---- compute: 18 K-steps x (2 ds_read_b128 + 2 MFMA), B from regs ----
        float4v acc[2];
#pragma unroll
        for (int i = 0; i < 2; ++i) acc[i] = (float4v){0.f, 0.f, 0.f, 0.f};
#pragma unroll
        for (int u = 0; u < 18; ++u) {
#pragma unroll
            for (int i = 0; i < 2; ++i) {
                const short8 a = *(const short8*)
                    &As[cur * TILE_SH + u * 1024 + (16 * i + ln) * 32 + hl * 8];
                acc[i] = __builtin_amdgcn_mfma_f32_16x16x32_bf16(a, Bv[u], acc[i], 0, 0, 0);
            }
        }
        bar_plain();                        // sync1: As[cur] reads done (program
                                            // order); stage(t+1) stays IN FLIGHT

        // ---- epilogue into the just-freed buffer (cur) ----
        float* Ot = (float*)&As[cur * TILE_SH];       // 32 x 65 floats = 8.3 KB
#pragma unroll
        for (int i = 0; i < 2; ++i)
#pragma unroll
            for (int r = 0; r < 4; ++r)
                Ot[(16 * i + 4 * hl + r) * LDO + 16 * wv + ln] = acc[i][r] + bv;
        bar_lgkm();                         // sync2: Ot visible; vm still in flight
        {
            const int p2 = p00 + t * PIXT + pp;
            if (p2 < NPIX) {
#pragma unroll
                for (int k = 0; k < 8; ++k) {
                    const int rid = k * 16 + rr;      // 0..127 = b2*64 + o
                    const int b2  = rid >> 6;
                    const int o   = rid & 63;
                    out[((b0 + b2) * COUT + o) * NPIX + p2] = Ot[(pp * 2 + b2) * LDO + o];
                }
            }
        }
        bar_full();                         // sync3: stage(t+1) drained with
                                            // compute+epilogue+store cover;
                                            // Ot region free for reuse
    }
#undef STAGE
}

// ---------------- fallback (round-1 kernel) if ws too small ----------------
#define FKC   72
#define FLDA  76
__global__ __launch_bounds__(256, 4)
void sconv2davg_fallback(const float* __restrict__ in,
                         const float* __restrict__ wgt,
                         const float* __restrict__ bias,
                         const int* __restrict__ selh,
                         const int* __restrict__ selw,
                         float* __restrict__ out) {
    __shared__ float As[64 * FLDA];
    __shared__ float Ws[64 * FLDA];
    __shared__ int hb_s[4], wb_s[4];
    const int tid = threadIdx.x;
    const int p0  = blockIdx.x * 4;
    if (tid < 4) {
        int p = p0 + tid;
        if (p > NPIX - 1) p = NPIX - 1;
        int y = p / OW;
        int x = p - y * OW;
        hb_s[tid] = 2 * y + selh[p];
        wb_s[tid] = 2 * x + selw[p];
    }
    __syncthreads();
    const int tn = tid & 15, tm = tid >> 4;
    float acc[4][4];
#pragma unroll
    for (int i = 0; i < 4; ++i)
#pragma unroll
        for (int j = 0; j < 4; ++j) acc[i][j] = 0.0f;
    for (int cc = 0; cc < 8; ++cc) {
        const int c0 = cc * 8;
#pragma unroll
        for (int it = 0; it < 18; ++it) {
            int idx = tid + it * 256;
            int m = idx / FKC, rem = idx - m * FKC;
            int cl = rem / 9, r = rem - cl * 9;
            int kh = r / 3, kw = r - kh * 3;
            As[m * FLDA + rem] =
                in[((((m & 15) * CIN) + (c0 + cl)) * H_ + hb_s[m >> 4] + kh) * W_ + wb_s[m >> 4] + kw];
        }
#pragma unroll
        for (int it = 0; it < 18; ++it) {
            int idx = tid + it * 256;
            int o = idx / FKC, kk = idx - o * FKC;
            Ws[o * FLDA + kk] = wgt[o * KTOT + cc * FKC + kk];
        }
        __syncthreads();
#pragma unroll 2
        for (int k0 = 0; k0 < FKC; k0 += 4) {
            float4 a[4], w[4];
#pragma unroll
            for (int i = 0; i < 4; ++i) a[i] = *(const float4*)&As[(4 * tm + i) * FLDA + k0];
#pragma unroll
            for (int j = 0; j < 4; ++j) w[j] = *(const float4*)&Ws[(tn + 16 * j) * FLDA + k0];
#pragma unroll
            for (int i = 0; i < 4; ++i)
#pragma unroll
                for (int j = 0; j < 4; ++j) {
                    acc[i][j] += a[i].x * w[j].x; acc[i][j] += a[i].y * w[j].y;
                    acc[i][j] += a[i].z * w[j].z; acc[i][j] += a[i].w * w[j].w;
                }
        }
        __syncthreads();
    }
    const int p = p0 + (tm >> 2);
    if (p < NPIX) {
#pragma unroll
        for (int i = 0; i < 4; ++i) {
            int b = (tm & 3) * 4 + i;
#pragma unroll
            for (int j = 0; j < 4; ++j)
                out[((b * COUT) + tn + 16 * j) * NPIX + p] = acc[i][j] + bias[tn + 16 * j];
        }
    }
}

extern "C" void kernel_launch(void* const* d_in, const int* in_sizes, int n_in,
                              void* d_out, int out_size, void* d_ws, size_t ws_size,
                              hipStream_t stream) {
    const float* in   = (const float*)d_in[0];
    const float* wgt  = (const float*)d_in[1];
    const float* bias = (const float*)d_in[2];
    const int*   selh = (const int*)d_in[3];
    const int*   selw = (const int*)d_in[4];
    float* out = (float*)d_out;

    const size_t nhwc_elems = (size_t)B_ * H_ * W_ * CIN;            // 16.7M bf16
    const size_t need = (nhwc_elems + (size_t)COUT * KTOT) * 2;      // ~33.6 MB

    if (ws_size >= need) {
        short* nhwc  = (short*)d_ws;
        short* wgt_t = nhwc + nhwc_elems;
        // y==H_ slice of the grid does the weight repack (32 blocks)
        repack_bf16<<<dim3(W_ / 64, H_ + 1, B_), 256, 0, stream>>>(in, wgt, nhwc, wgt_t);
        const int pblocks = (NPIX + PIXT * NT - 1) / (PIXT * NT);    // 63
        sconv2davg_mfma<<<dim3(pblocks * (B_ / BT)), 256, 0, stream>>>(
            nhwc, wgt_t, bias, selh, selw, out);
    } else {
        sconv2davg_fallback<<<(NPIX + 3) / 4, 256, 0, stream>>>(
            in, wgt, bias, selh, selw, out);
    }
}